// Round 1
// 477.311 us; speedup vs baseline: 1.0618x; 1.0618x over previous
//
#include <hip/hip_runtime.h>
#include <hip/hip_bf16.h>
#include <cstddef>

// Bn=256, N=197, C=192, H=3, hd=64, E=1024, hid=768, M = Bn*N = 50432 = 394*128
//
// ws layout (bytes):
//   [0,          77463552)   : msgbuf bf16 [1024][197][192]  -- later overlaid by h1 bf16 [50432][768]
//   [77463552,  116195328)   : qk  bf16 [50432][384]   (Q cols 0..191, K cols 192..383)
//   [116195328, 135561216)   : xn  bf16 [50432][192]   (reused as x2n after proj)
//   [135561216, 154927104)   : agg bf16 [50432][192]
//   [154927104, 174587904)   : vt  bf16 [256][3][64][200]  (V transposed, t contiguous; cols 197..199 garbage)
//   [174587904, 175472640)   : bf16 weights (qkv, proj, fc1, fc2)
//   [175472640, 175473664)   : cnt int32[256]

typedef __attribute__((ext_vector_type(8))) short bf8_t;
typedef __attribute__((ext_vector_type(4))) float f4_t;

__device__ __forceinline__ float bf2f(unsigned short u) {
  union { unsigned int i; float f; } x; x.i = ((unsigned int)u) << 16; return x.f;
}
__device__ __forceinline__ unsigned short f2bf(float f) {
  unsigned int u = __builtin_bit_cast(unsigned int, f);
  u = (u + 0x7FFFu + ((u >> 16) & 1u)) >> 16;
  return (unsigned short)u;
}
// packed f32x2 -> bf16x2 (RTNE), single VALU op (no builtin on gfx950)
__device__ __forceinline__ unsigned int cvt_pk_bf16(float a, float b) {
  unsigned int r;
  asm("v_cvt_pk_bf16_f32 %0, %1, %2" : "=v"(r) : "v"(a), "v"(b));
  return r;
}

// ---------------------------------------------------------------------------
__global__ __launch_bounds__(256) void f2bf_kernel(const float* __restrict__ src,
                                                   unsigned short* __restrict__ dst, int n) {
  int i = blockIdx.x * 256 + threadIdx.x;
  if (i < n) dst[i] = f2bf(src[i]);
}

// ---------------------------------------------------------------------------
// LayerNorm(fp32 in) -> bf16 out.  One wave per row (C=192, 3 elems/lane).
// ---------------------------------------------------------------------------
__global__ __launch_bounds__(256) void ln_bf16_kernel(const float* __restrict__ X,
    const float* __restrict__ g, const float* __restrict__ b,
    unsigned short* __restrict__ Y) {
  int row = blockIdx.x * 4 + (threadIdx.x >> 6);
  int lane = threadIdx.x & 63;
  const float* xr = X + (size_t)row * 192;
  float v0 = xr[lane], v1 = xr[lane + 64], v2 = xr[lane + 128];
  float s = v0 + v1 + v2, ss = v0 * v0 + v1 * v1 + v2 * v2;
#pragma unroll
  for (int o = 32; o > 0; o >>= 1) { s += __shfl_xor(s, o, 64); ss += __shfl_xor(ss, o, 64); }
  float mean = s * (1.f / 192.f);
  float var = ss * (1.f / 192.f) - mean * mean;
  float r = rsqrtf(var + 1e-5f);
  unsigned short* yr = Y + (size_t)row * 192;
  yr[lane]       = f2bf((v0 - mean) * r * g[lane]       + b[lane]);
  yr[lane + 64]  = f2bf((v1 - mean) * r * g[lane + 64]  + b[lane + 64]);
  yr[lane + 128] = f2bf((v2 - mean) * r * g[lane + 128] + b[lane + 128]);
}

// ---------------------------------------------------------------------------
// bf16 MFMA GEMM: C = f( A @ W^T ), tile 128x64, 4 waves.
// MODE 0: qkv -> qk bf16 (cols<384) + vt bf16 transposed (cols>=384)
// MODE 1: proj -> f32 (/cnt, +bias, +xres)
// MODE 2: fc1 -> bf16 gelu(+bias)
// MODE 3: fc2 -> f32 (+bias, +xres; in-place safe per-element)
// ---------------------------------------------------------------------------
template<int MODE, int NK>
__global__ __launch_bounds__(256) void gemm_bf16(
    const unsigned short* __restrict__ A, const unsigned short* __restrict__ W,
    const float* __restrict__ bias, const float* __restrict__ xres,
    const int* __restrict__ cntg, void* __restrict__ Cout,
    unsigned short* __restrict__ Cvt, int ldc) {
  constexpr int LDA = 200;
  __shared__ unsigned short As[128 * LDA];
  __shared__ unsigned short Ws[64 * LDA];
  const int tid = threadIdx.x;
  const int m0 = blockIdx.x * 128, n0 = blockIdx.y * 64;
  const int wave = tid >> 6, lane = tid & 63;
  const int mfrag = lane & 15, quad = lane >> 4;
  const int K = NK * 192;

  f4_t acc[2][4];
#pragma unroll
  for (int i = 0; i < 2; ++i)
#pragma unroll
    for (int j = 0; j < 4; ++j) acc[i][j] = (f4_t){0.f, 0.f, 0.f, 0.f};

  for (int kc = 0; kc < NK; ++kc) {
    __syncthreads();
#pragma unroll
    for (int it = 0; it < 12; ++it) {
      int idx = it * 256 + tid;
      int r = idx / 24, c = idx % 24;
      *(float4*)(As + r * LDA + c * 8) =
          *(const float4*)(A + (size_t)(m0 + r) * K + kc * 192 + c * 8);
    }
#pragma unroll
    for (int it = 0; it < 6; ++it) {
      int idx = it * 256 + tid;
      int r = idx / 24, c = idx % 24;
      *(float4*)(Ws + r * LDA + c * 8) =
          *(const float4*)(W + (size_t)(n0 + r) * K + kc * 192 + c * 8);
    }
    __syncthreads();
#pragma unroll
    for (int ks = 0; ks < 6; ++ks) {
      bf8_t a0 = *(const bf8_t*)(As + (wave * 32 + mfrag) * LDA + ks * 32 + quad * 8);
      bf8_t a1 = *(const bf8_t*)(As + (wave * 32 + 16 + mfrag) * LDA + ks * 32 + quad * 8);
#pragma unroll
      for (int nt = 0; nt < 4; ++nt) {
        bf8_t bf = *(const bf8_t*)(Ws + (nt * 16 + mfrag) * LDA + ks * 32 + quad * 8);
        acc[0][nt] = __builtin_amdgcn_mfma_f32_16x16x32_bf16(a0, bf, acc[0][nt], 0, 0, 0);
        acc[1][nt] = __builtin_amdgcn_mfma_f32_16x16x32_bf16(a1, bf, acc[1][nt], 0, 0, 0);
      }
    }
  }

#pragma unroll
  for (int mt = 0; mt < 2; ++mt)
#pragma unroll
    for (int nt = 0; nt < 4; ++nt)
#pragma unroll
      for (int reg = 0; reg < 4; ++reg) {
        int row = m0 + wave * 32 + mt * 16 + quad * 4 + reg;
        int col = n0 + nt * 16 + mfrag;
        float v = acc[mt][nt][reg];
        if constexpr (MODE == 0) {
          if (col < 384) {
            ((unsigned short*)Cout)[(size_t)row * 384 + col] = f2bf(v);
          } else {
            int cc = col - 384, hh = cc >> 6, dd = cc & 63;
            int bb = row / 197, tt = row - bb * 197;
            Cvt[((size_t)(bb * 3 + hh) * 64 + dd) * 200 + tt] = f2bf(v);
          }
        } else if constexpr (MODE == 1) {
          int c = cntg[row / 197];
          v = (c > 0) ? v / (float)c + bias[col] : 0.f;
          v += xres[(size_t)row * 192 + col];
          ((float*)Cout)[(size_t)row * ldc + col] = v;
        } else if constexpr (MODE == 2) {
          v += bias[col];
          v = 0.5f * v * (1.f + erff(v * 0.70710678118654752f));
          ((unsigned short*)Cout)[(size_t)row * ldc + col] = f2bf(v);
        } else {
          v += bias[col] + xres[(size_t)row * 192 + col];
          ((float*)Cout)[(size_t)row * ldc + col] = v;
        }
      }
}

// ---------------------------------------------------------------------------
// MFMA attention, one block per (edge e, head h).  q,v from dst; k from src.
// 512 threads / 8 waves (2 blocks/CU -> 16 waves/CU, was 8 with 4-wave blocks).
// K staged row-major from qk; V^T staged row-major from pre-transposed vt.
// S = Q@K^T, exact softmax in regs (exp2-folded scale, tail-only masking),
// P->LDS (single wave-private buffer, in-order DS) -> PV.
// ---------------------------------------------------------------------------
__global__ __launch_bounds__(512) void attnA_kernel(
    const unsigned short* __restrict__ qk, const unsigned short* __restrict__ vtg,
    const int* __restrict__ edge, unsigned short* __restrict__ msgbuf) {
  const int e = blockIdx.x, h = blockIdx.y;
  const int s = edge[e], b = edge[1024 + e];
  __shared__ unsigned short Ks[208 * 72];
  __shared__ unsigned short Vt[64 * 232];
  __shared__ unsigned short Ps[8][640];   // [wave][16*40], single buffer (DS in-order per wave)
  const int tid = threadIdx.x;
  const int wave = tid >> 6, lane = tid & 63;
  const int mfrag = lane & 15, quad = lane >> 4;

  // stage K rows (src s), coalesced 16B, conflict-free
  for (int i = tid; i < 197 * 8; i += 512) {
    int m = i >> 3, c8 = i & 7;
    *(float4*)(Ks + m * 72 + c8 * 8) =
        *(const float4*)(qk + (size_t)(s * 197 + m) * 384 + 192 + h * 64 + c8 * 8);
  }
  // stage V^T rows (dst b) from pre-transposed global, b128 conflict-free
  for (int i = tid; i < 64 * 25; i += 512) {
    int d = i / 25, c8 = i - d * 25;
    *(float4*)(Vt + d * 232 + c8 * 8) =
        *(const float4*)(vtg + ((size_t)(b * 3 + h) * 64 + d) * 200 + c8 * 8);
  }
  __syncthreads();
  // zero pad keys 197..231 (197..199 overwrite staged garbage)
  for (int i = tid; i < 64 * 35; i += 512) {
    int d = i / 35, kk = 197 + (i - d * 35);
    Vt[d * 232 + kk] = 0;
  }
  __syncthreads();

  for (int st = wave; st < 13; st += 8) {
    const int m0 = st * 16;
    const size_t qrow = (size_t)(b * 197 + min(m0 + mfrag, 196)) * 384 + h * 64;
    bf8_t a0 = *(const bf8_t*)(qk + qrow + quad * 8);
    bf8_t a1 = *(const bf8_t*)(qk + qrow + 32 + quad * 8);

    f4_t S[13];
#pragma unroll
    for (int nt = 0; nt < 13; ++nt) {
      bf8_t k0 = *(const bf8_t*)(Ks + (nt * 16 + mfrag) * 72 + quad * 8);
      bf8_t k1 = *(const bf8_t*)(Ks + (nt * 16 + mfrag) * 72 + 32 + quad * 8);
      f4_t z = (f4_t){0.f, 0.f, 0.f, 0.f};
      z = __builtin_amdgcn_mfma_f32_16x16x32_bf16(a0, k0, z, 0, 0, 0);
      S[nt] = __builtin_amdgcn_mfma_f32_16x16x32_bf16(a1, k1, z, 0, 0, 0);
    }

    // exact softmax over keys; lane holds S[q=quad*4+reg][key=nt*16+mfrag].
    // only nt=12 has invalid keys (192..207): mask those lanes once.
#pragma unroll
    for (int reg = 0; reg < 4; ++reg)
      S[12][reg] = (mfrag < 5) ? S[12][reg] : -1e30f;

    float mx[4] = {-1e30f, -1e30f, -1e30f, -1e30f};
#pragma unroll
    for (int nt = 0; nt < 13; ++nt)
#pragma unroll
      for (int reg = 0; reg < 4; ++reg) mx[reg] = fmaxf(mx[reg], S[nt][reg]);
#pragma unroll
    for (int off = 1; off < 16; off <<= 1)
#pragma unroll
      for (int reg = 0; reg < 4; ++reg) mx[reg] = fmaxf(mx[reg], __shfl_xor(mx[reg], off, 64));

    // p = exp(0.125*(s-m)) = exp2(0.18033688*(s-m)); masked entries -> 0
    constexpr float CEXP = 0.18033688011112042f;
    float sum[4] = {0.f, 0.f, 0.f, 0.f};
#pragma unroll
    for (int nt = 0; nt < 13; ++nt)
#pragma unroll
      for (int reg = 0; reg < 4; ++reg) {
        float p = exp2f((S[nt][reg] - mx[reg]) * CEXP);
        S[nt][reg] = p;
        sum[reg] += p;
      }
#pragma unroll
    for (int off = 1; off < 16; off <<= 1)
#pragma unroll
      for (int reg = 0; reg < 4; ++reg) sum[reg] += __shfl_xor(sum[reg], off, 64);
    float inv[4];
#pragma unroll
    for (int reg = 0; reg < 4; ++reg) inv[reg] = __builtin_amdgcn_rcpf(sum[reg]);

    // PV: chunked P->LDS (wave-private; DS in-order per wave makes the
    // single buffer safe: the pf read of chunk kt is issued before chunk
    // kt+1's writes and the DS pipe processes same-wave ops in order).
    f4_t o[4];
#pragma unroll
    for (int dt = 0; dt < 4; ++dt) o[dt] = (f4_t){0.f, 0.f, 0.f, 0.f};
    unsigned short* buf = Ps[wave];
#pragma unroll
    for (int kt = 0; kt < 7; ++kt) {
#pragma unroll
      for (int reg = 0; reg < 4; ++reg) {
        float p0 = S[kt * 2][reg];
        float p1 = (kt * 2 + 1 < 13) ? S[kt * 2 + 1][reg] : 0.f;
        unsigned int u = cvt_pk_bf16(p0, p1);
        buf[(quad * 4 + reg) * 40 + mfrag]      = (unsigned short)u;
        buf[(quad * 4 + reg) * 40 + 16 + mfrag] = (unsigned short)(u >> 16);
      }
      bf8_t pf = *(const bf8_t*)(buf + mfrag * 40 + quad * 8);
#pragma unroll
      for (int dt = 0; dt < 4; ++dt) {
        bf8_t vf = *(const bf8_t*)(Vt + (dt * 16 + mfrag) * 232 + kt * 32 + quad * 8);
        o[dt] = __builtin_amdgcn_mfma_f32_16x16x32_bf16(pf, vf, o[dt], 0, 0, 0);
      }
    }

    // msg store: lane holds o[dt][reg] = out[q=quad*4+reg][d=dt*16+mfrag]
#pragma unroll
    for (int dt = 0; dt < 4; dt += 2)
#pragma unroll
      for (int reg = 0; reg < 4; ++reg) {
        int q = m0 + quad * 4 + reg;
        unsigned int u = cvt_pk_bf16(o[dt][reg] * inv[reg], o[dt + 1][reg] * inv[reg]);
        if (q < 197) {
          size_t base = (size_t)e * 37824 + q * 192 + h * 64 + dt * 16 + mfrag;
          msgbuf[base]      = (unsigned short)u;
          msgbuf[base + 16] = (unsigned short)(u >> 16);
        }
      }
  }
}

// ---------------------------------------------------------------------------
// Per-dst aggregation, bf16x8 vectorized.  grid (256 dst, 4 chunks).
// ---------------------------------------------------------------------------
__global__ __launch_bounds__(256) void aggregate_kernel(
    const unsigned short* __restrict__ msgbuf, const int* __restrict__ edge,
    unsigned short* __restrict__ agg, int* __restrict__ cntg) {
  const int b = blockIdx.x, chunk = blockIdx.y;
  __shared__ int list[1024];
  __shared__ int lc;
  const int tid = threadIdx.x;
  if (tid == 0) lc = 0;
  __syncthreads();
  for (int e = tid; e < 1024; e += 256)
    if (edge[1024 + e] == b) { int p = atomicAdd(&lc, 1); list[p] = e; }
  __syncthreads();
  const int cnt = lc;
  if (chunk == 0 && tid == 0) cntg[b] = cnt;
  const int base = chunk * 9456;  // 37824 = 4*9456, 9456 = 1182*8
  for (int i8 = tid; i8 < 1182; i8 += 256) {
    int i = base + i8 * 8;
    float sum[8];
#pragma unroll
    for (int kk = 0; kk < 8; ++kk) sum[kk] = 0.f;
    for (int j = 0; j < cnt; ++j) {
      float4 t = *(const float4*)(msgbuf + (size_t)list[j] * 37824 + i);
      const unsigned short* u = (const unsigned short*)&t;
#pragma unroll
      for (int kk = 0; kk < 8; ++kk) sum[kk] += bf2f(u[kk]);
    }
    unsigned short o[8];
#pragma unroll
    for (int kk = 0; kk < 8; ++kk) o[kk] = f2bf(sum[kk]);
    *(float4*)(agg + (size_t)b * 37824 + i) = *(const float4*)o;
  }
}

// ---------------------------------------------------------------------------
extern "C" void kernel_launch(void* const* d_in, const int* in_sizes, int n_in,
                              void* d_out, int out_size, void* d_ws, size_t ws_size,
                              hipStream_t stream) {
  const float* x      = (const float*)d_in[0];
  const int*   edge   = (const int*)d_in[1];
  const float* n1g    = (const float*)d_in[2];
  const float* n1b    = (const float*)d_in[3];
  const float* qkv_w  = (const float*)d_in[4];
  const float* proj_w = (const float*)d_in[5];
  const float* proj_b = (const float*)d_in[6];
  const float* n2g    = (const float*)d_in[7];
  const float* n2b    = (const float*)d_in[8];
  const float* fc1_w  = (const float*)d_in[9];
  const float* fc1_b  = (const float*)d_in[10];
  const float* fc2_w  = (const float*)d_in[11];
  const float* fc2_b  = (const float*)d_in[12];
  float* out = (float*)d_out;

  char* ws = (char*)d_ws;
  unsigned short* msgbuf = (unsigned short*)ws;
  unsigned short* h1     = (unsigned short*)ws;                    // overlays msgbuf
  unsigned short* qk     = (unsigned short*)(ws + 77463552);
  unsigned short* xn     = (unsigned short*)(ws + 116195328);
  unsigned short* agg    = (unsigned short*)(ws + 135561216);
  unsigned short* vtg    = (unsigned short*)(ws + 154927104);
  unsigned short* wqkv   = (unsigned short*)(ws + 174587904);
  unsigned short* wproj  = (unsigned short*)(ws + 174809088);
  unsigned short* wfc1   = (unsigned short*)(ws + 174882816);
  unsigned short* wfc2   = (unsigned short*)(ws + 175177728);
  int*            cntg   = (int*)           (ws + 175472640);

  dim3 blk(256);
  f2bf_kernel<<<dim3(432), blk, 0, stream>>>(qkv_w, wqkv, 110592);
  f2bf_kernel<<<dim3(144), blk, 0, stream>>>(proj_w, wproj, 36864);
  f2bf_kernel<<<dim3(576), blk, 0, stream>>>(fc1_w, wfc1, 147456);
  f2bf_kernel<<<dim3(576), blk, 0, stream>>>(fc2_w, wfc2, 147456);

  ln_bf16_kernel<<<dim3(12608), blk, 0, stream>>>(x, n1g, n1b, xn);
  gemm_bf16<0, 1><<<dim3(394, 9), blk, 0, stream>>>(xn, wqkv, nullptr, nullptr, nullptr, qk, vtg, 384);
  attnA_kernel<<<dim3(1024, 3), dim3(512), 0, stream>>>(qk, vtg, edge, msgbuf);
  aggregate_kernel<<<dim3(256, 4), blk, 0, stream>>>(msgbuf, edge, agg, cntg);
  gemm_bf16<1, 1><<<dim3(394, 3), blk, 0, stream>>>(agg, wproj, proj_b, x, cntg, out, nullptr, 192);
  ln_bf16_kernel<<<dim3(12608), blk, 0, stream>>>(out, n2g, n2b, xn);
  gemm_bf16<2, 1><<<dim3(394, 12), blk, 0, stream>>>(xn, wfc1, fc1_b, nullptr, nullptr, h1, nullptr, 768);
  gemm_bf16<3, 4><<<dim3(394, 3), blk, 0, stream>>>(h1, wfc2, fc2_b, out, nullptr, out, nullptr, 192);
}